// Round 8
// baseline (23218.225 us; speedup 1.0000x reference)
//
#include <hip/hip_runtime.h>
#include <cstddef>
#include <cstdint>

#define HID     1024
#define BATCH   64
#define TSEQ    512
#define NB      (BATCH*HID)     // 65536 floats per slab
#define NBLK    256
#define NITER   515
#define RSTRIDE 20              // LDS reduction row stride (16 + pad 4)

// ---------------------------------------------------------------------------
// R8 = R7 (transposed slabs, 17.8 ms) + vector-path W engine.
//
// R7 counters: FETCH collapsed 6x but dur ~unchanged -> fetch wasn't binding.
// ~25 us/iter unaccounted; prime suspect: W streamed 64 KB/CU/iter through
// wave-uniform loads the compiler lifts to s_load (sL1 ~16KB -> 4x thrash
// every iter; lgkmcnt-blocking waits with only 2 waves/SIMD of cover).
// Fix: force W onto the VECTOR path via inline asm:
//   global_load_dwordx4 vdst, v_sec, s[Wc[c]] offset:{0,16,32}
// 16 SGPR-pair column bases, one uniform VGPR section offset (+32B per
// 2 sections) -> zero per-load address math. 4-k sections, W double-buffered
// in VGPRs (2x16 quads = 128 VGPR), h loads in the same vmcnt FIFO,
// distance-1 prefetch, counted WAITV(20/17).
//
// ws layout / coherence model: identical to R7 (P-slot rotation, sc1
// write-through stores, plain cached loads, agent-acquire fence every P).
// ---------------------------------------------------------------------------

typedef __attribute__((ext_vector_type(4))) float f32x4;
typedef __attribute__((ext_vector_type(2))) float f32x2;

#define WAITV(N) do { asm volatile("s_waitcnt vmcnt(" #N ")" ::: "memory"); \
                      __builtin_amdgcn_sched_barrier(0); } while (0)

// W load: uniform SGPR base + uniform section-offset VGPR + literal imm.
#define WLOAD(dst, base, voff, imm) \
  asm volatile("global_load_dwordx4 %0, %1, %2 offset:" #imm \
               : "=v"(dst) : "v"(voff), "s"(base) : "memory")

// Transposed h load: lane pointer + literal imm (k-steps are 256B apart).
#define HLOAD1(dst, p, imm) \
  asm volatile("global_load_dword %0, %1, off offset:" #imm \
               : "=v"(dst) : "v"(p) : "memory")

// Row-major h load (x path): 4 consecutive floats.
#define HLOAD4(dst, p) \
  asm volatile("global_load_dwordx4 %0, %1, off" : "=v"(dst) : "v"(p) : "memory")

__device__ __forceinline__ void gstore2_coh(float* p, f32x2 v) {
  asm volatile("global_store_dwordx2 %0, %1, off sc1" :: "v"(p), "v"(v) : "memory");
}

__device__ __forceinline__ void gbar(unsigned* bar, unsigned target) {
  asm volatile("s_waitcnt vmcnt(0)" ::: "memory");
  __syncthreads();
  if (threadIdx.x == 0) {
    __hip_atomic_fetch_add(bar, 1u, __ATOMIC_RELAXED, __HIP_MEMORY_SCOPE_AGENT);
    while (__hip_atomic_load(bar, __ATOMIC_RELAXED, __HIP_MEMORY_SCOPE_AGENT) < target) {
      __builtin_amdgcn_s_sleep(1);
    }
  }
  __syncthreads();
}

// One 4-k x 16-col FMA section (32 packed f32x2 FMAs -> v_pk_fma_f32).
__device__ __forceinline__ void fma_sec(f32x2 (&acc)[16], const f32x4 (&Wq)[16],
                                        float h0, float h1, float h2, float h3) {
#pragma unroll
  for (int c = 0; c < 16; ++c) {
    f32x2 s = acc[c];
    s += f32x2{h0, h1} * f32x2{Wq[c].x, Wq[c].y};
    s += f32x2{h2, h3} * f32x2{Wq[c].z, Wq[c].w};
    acc[c] = s;
  }
}

// --- engine T: transposed slab h (roles 0,1,2) ------------------------------
// hTb = slabT + b; wave k-slice [k0, k0+128). Section s: k = k0+4s+j.
__device__ __forceinline__ void engineT(const float* hTb, int k0,
                                        const float* const (&Wc)[16],
                                        f32x2 (&acc)[16]) {
  f32x4 WA[16], WB[16];
  float a0, a1, a2, a3, b0, b1, b2, b3;
  const float* hp = hTb + (size_t)k0 * 64;
  unsigned vs = 0;                       // section byte-offset into W row
  // prologue: section 0 -> A
  HLOAD1(a0, hp, 0); HLOAD1(a1, hp, 256); HLOAD1(a2, hp, 512); HLOAD1(a3, hp, 768);
#pragma unroll
  for (int c = 0; c < 16; ++c) WLOAD(WA[c], Wc[c], vs, 0);
  hp += 256;
#pragma unroll 1
  for (int g = 0; g < 15; ++g) {
    // issue B = section 2g+1  (imm 16 = vs+16 = (2g+1)*16)
    HLOAD1(b0, hp, 0); HLOAD1(b1, hp, 256); HLOAD1(b2, hp, 512); HLOAD1(b3, hp, 768);
#pragma unroll
    for (int c = 0; c < 16; ++c) WLOAD(WB[c], Wc[c], vs, 16);
    hp += 256;
    WAITV(20);
    fma_sec(acc, WA, a0, a1, a2, a3);
    // issue A = section 2g+2  (imm 32)
    HLOAD1(a0, hp, 0); HLOAD1(a1, hp, 256); HLOAD1(a2, hp, 512); HLOAD1(a3, hp, 768);
#pragma unroll
    for (int c = 0; c < 16; ++c) WLOAD(WA[c], Wc[c], vs, 32);
    hp += 256;
    vs += 32;
    WAITV(20);
    fma_sec(acc, WB, b0, b1, b2, b3);
  }
  // tail: sections 30 (in A) and 31
  HLOAD1(b0, hp, 0); HLOAD1(b1, hp, 256); HLOAD1(b2, hp, 512); HLOAD1(b3, hp, 768);
#pragma unroll
  for (int c = 0; c < 16; ++c) WLOAD(WB[c], Wc[c], vs, 16);
  WAITV(20);
  fma_sec(acc, WA, a0, a1, a2, a3);
  WAITV(0);
  fma_sec(acc, WB, b0, b1, b2, b3);
}

// --- engine X: row-major h (role 3, x input) --------------------------------
__device__ __forceinline__ void engineX(const float* hb,
                                        const float* const (&Wc)[16],
                                        f32x2 (&acc)[16]) {
  f32x4 WA[16], WB[16];
  f32x4 ha, hbv;
  const float* hp = hb;
  unsigned vs = 0;
  HLOAD4(ha, hp);
#pragma unroll
  for (int c = 0; c < 16; ++c) WLOAD(WA[c], Wc[c], vs, 0);
  hp += 4;
#pragma unroll 1
  for (int g = 0; g < 15; ++g) {
    HLOAD4(hbv, hp);
#pragma unroll
    for (int c = 0; c < 16; ++c) WLOAD(WB[c], Wc[c], vs, 16);
    hp += 4;
    WAITV(17);
    fma_sec(acc, WA, ha.x, ha.y, ha.z, ha.w);
    HLOAD4(ha, hp);
#pragma unroll
    for (int c = 0; c < 16; ++c) WLOAD(WA[c], Wc[c], vs, 32);
    hp += 4;
    vs += 32;
    WAITV(17);
    fma_sec(acc, WB, hbv.x, hbv.y, hbv.z, hbv.w);
  }
  HLOAD4(hbv, hp);
#pragma unroll
  for (int c = 0; c < 16; ++c) WLOAD(WB[c], Wc[c], vs, 16);
  WAITV(17);
  fma_sec(acc, WA, ha.x, ha.y, ha.z, ha.w);
  WAITV(0);
  fma_sec(acc, WB, hbv.x, hbv.y, hbv.z, hbv.w);
}

// ---------------------------------------------------------------------------
__global__ __launch_bounds__(256) void init_hT(
    const float* __restrict__ h0_init, float* __restrict__ ws,
    unsigned P, unsigned mask)
{
  const int g = blockIdx.x * 256 + threadIdx.x;   // 0..131071 (grid 512)
  const int l = g >> 16;
  const int r = g & 65535;                        // r = k*64 + b
  const int k = r >> 6;
  const int b = r & 63;
  float* base = ws + (size_t)l * P * NB + (size_t)mask * NB;
  base[r] = h0_init[(size_t)l * NB + (size_t)b * HID + k];
}

// ---------------------------------------------------------------------------
// Roles (blk>>6), iteration i:
//   3: ig0T[t=i]   = (x[t] @ Wx0^T + b)^T            -> io[t] (sc1)
//   0: h0T[t=i-1]  = tanh(ig0T[t] + (h0[t-1]@Wh0^T)^T) -> slot (sc1)
//   1: ig1T[t=i-2] = (h0[t] @ Wx1^T + b)^T           -> slot  (sc1)
//   2: h1T[t=i-3]  = tanh(ig1T[t] + ...) -> slot (sc1); io[t]=10*h1 [B][H]
// ---------------------------------------------------------------------------
__global__ __launch_bounds__(512, 2) void rnn_step(
    const float* __restrict__ x,
    float* io,
    const float* __restrict__ Wx,       // [2][H][H]
    const float* __restrict__ Wh,       // [2][H][H]
    const float* __restrict__ bx,       // [2][H]
    const float* __restrict__ bh,       // [2][H]
    float* __restrict__ ws,
    unsigned P, unsigned mask)
{
  __shared__ __align__(16) float red[8 * 64 * RSTRIDE];   // 40 KB
  const int tid  = threadIdx.x;
  const int blk  = blockIdx.x;
  const int role = blk >> 6;                 // 0..3
  const int c0   = (blk & 63) << 4;          // 16 cols per block
  const int b    = tid & 63;                 // compute lane = batch row
  const int kq   = __builtin_amdgcn_readfirstlane(tid >> 6); // wave 0..7
  const int k0   = kq * 128;                 // this wave's K-slice

  float* h0base = ws;
  float* h1base = ws + (size_t)P * NB;
  float* igbase = ws + (size_t)2 * P * NB;
  unsigned* bar = (unsigned*)(ws + (size_t)3 * P * NB);

  const float* W = (role == 3) ? Wx
                 : (role == 0) ? Wh
                 : (role == 1) ? (Wx + (size_t)HID * HID)
                 :               (Wh + (size_t)HID * HID);
  // 16 uniform column-base pointers (SGPR pairs for the asm W loads).
  const float* Wc[16];
#pragma unroll
  for (int c = 0; c < 16; ++c) Wc[c] = W + (size_t)(c0 + c) * HID + k0;

  // Epilogue mapping: thread -> (col cE, batches bE,bE+1); transposed store
  // offset rbT is coalesced dwordx2.
  const int cE = tid >> 5;                   // 0..15
  const int bE = (tid & 31) << 1;            // 0..62 even
  const size_t rbT = (size_t)(c0 + cE) * 64 + bE;

  float bsum = 0.f;
  if (role == 1)      bsum = bx[HID + c0 + cE] + bh[HID + c0 + cE];
  else if (role == 3) bsum = bx[c0 + cE]       + bh[c0 + cE];

  for (int i = 0; i < NITER; ++i) {
    if ((i & (int)mask) == 0 && i) {
      __builtin_amdgcn_fence(__ATOMIC_ACQUIRE, "agent");   // every P iters
    }

    bool active;
    int t;
    const float* src;
    if (role == 3)      { t = i;     active = (i <= 511);           src = x + (size_t)t * NB; }
    else if (role == 0) { t = i - 1; active = (i >= 1 && i <= 512);
                          src = h0base + (size_t)((t - 1) & (int)mask) * NB; }
    else if (role == 1) { t = i - 2; active = (i >= 2 && i <= 513);
                          src = h0base + (size_t)(t & (int)mask) * NB; }
    else                { t = i - 3; active = (i >= 3 && i <= 514);
                          src = h1base + (size_t)((t - 1) & (int)mask) * NB; }

    if (active) {
      f32x2 acc[16];
#pragma unroll
      for (int c = 0; c < 16; ++c) acc[c] = f32x2{0.f, 0.f};

      if (role == 3) engineX(src + (size_t)b * HID + k0, Wc, acc);
      else           engineT(src + b, k0, Wc, acc);

      // Epilogue operands (all asm loads drained by engine's WAITV(0)).
      f32x2 e = { 0.f, 0.f };
      if (role == 0)      e = *(const f32x2*)(io + (size_t)t * NB + rbT);
      else if (role == 2) e = *(const f32x2*)(igbase + (size_t)(t & (int)mask) * NB + rbT);

      float accs[16];
#pragma unroll
      for (int c = 0; c < 16; ++c) accs[c] = acc[c].x + acc[c].y;

      float* rrow = &red[(kq * 64 + b) * RSTRIDE];
      *(float4*)(rrow + 0)  = make_float4(accs[0],  accs[1],  accs[2],  accs[3]);
      *(float4*)(rrow + 4)  = make_float4(accs[4],  accs[5],  accs[6],  accs[7]);
      *(float4*)(rrow + 8)  = make_float4(accs[8],  accs[9],  accs[10], accs[11]);
      *(float4*)(rrow + 12) = make_float4(accs[12], accs[13], accs[14], accs[15]);
      __syncthreads();

      float s0 = 0.f, s1 = 0.f;
#pragma unroll
      for (int q = 0; q < 8; ++q) {
        s0 += red[(q * 64 + bE)     * RSTRIDE + cE];
        s1 += red[(q * 64 + bE + 1) * RSTRIDE + cE];
      }

      if (role == 3) {
        gstore2_coh(io + (size_t)t * NB + rbT, f32x2{ s0 + bsum, s1 + bsum });
      } else if (role == 0) {
        gstore2_coh(h0base + (size_t)(t & (int)mask) * NB + rbT,
                    f32x2{ tanhf(s0 + e.x), tanhf(s1 + e.y) });
      } else if (role == 1) {
        gstore2_coh(igbase + (size_t)(t & (int)mask) * NB + rbT,
                    f32x2{ s0 + bsum, s1 + bsum });
      } else {
        float t0 = tanhf(s0 + e.x);
        float t1 = tanhf(s1 + e.y);
        gstore2_coh(h1base + (size_t)(t & (int)mask) * NB + rbT, f32x2{ t0, t1 });
        io[(size_t)t * NB + (size_t)bE       * HID + c0 + cE] = 10.f * t0;
        io[(size_t)t * NB + (size_t)(bE + 1) * HID + c0 + cE] = 10.f * t1;
      }
    }
    gbar(bar, (unsigned)(NBLK * (i + 1)));
  }
}

// ---------------------------------------------------------------------------
__global__ __launch_bounds__(256) void finalize_hn(
    const float* __restrict__ ws, float* __restrict__ out, unsigned P, unsigned mask)
{
  const int g = blockIdx.x * 256 + threadIdx.x;     // 0..131071
  const int l = g >> 16;
  const int rem = g & 65535;                        // b*1024 + k
  const int bb = rem >> 10;
  const int kk = rem & 1023;
  const float* hf = ws + ((size_t)l * P + (511u & mask)) * NB;
  out[(size_t)TSEQ * NB + g] = hf[(size_t)kk * 64 + bb];
}

// ---------------------------------------------------------------------------
extern "C" void kernel_launch(void* const* d_in, const int* in_sizes, int n_in,
                              void* d_out, int out_size, void* d_ws, size_t ws_size,
                              hipStream_t stream) {
  const float* x  = (const float*)d_in[0];
  const float* h0 = (const float*)d_in[1];
  const float* Wx = (const float*)d_in[2];
  const float* bx = (const float*)d_in[3];
  const float* Wh = (const float*)d_in[4];
  const float* bh = (const float*)d_in[5];
  float* out = (float*)d_out;
  float* ws  = (float*)d_ws;

  unsigned P = 16;
  while (P > 2 && ((size_t)3 * P * NB + 16) * sizeof(float) > ws_size) P >>= 1;
  unsigned mask = P - 1;

  hipMemsetAsync(ws + (size_t)3 * P * NB, 0, sizeof(unsigned), stream);
  init_hT<<<dim3(512), dim3(256), 0, stream>>>(h0, ws, P, mask);

  float* io = out;
  void* args[] = { &x, &io, &Wx, &Wh, &bx, &bh, &ws, &P, &mask };
  hipLaunchCooperativeKernel((const void*)rnn_step, dim3(NBLK), dim3(512),
                             args, 0, stream);

  finalize_hn<<<dim3(512), dim3(256), 0, stream>>>(ws, out, P, mask);
}